// Round 1
// baseline (373.663 us; speedup 1.0000x reference)
//
#include <hip/hip_runtime.h>
#include <math.h>

#define BATCH 2
#define CH 64
#define WID 96
#define HEI 96
#define HWSZ 9216          // 96*96
#define EPSV 1e-8f
#define TM 128             // gemm tile (128x128), K = CH = 64 fully resident

// ---- order-preserving float<->uint encoding for atomicMax on floats ----
__device__ __forceinline__ unsigned enc_f(float f) {
    unsigned u = __float_as_uint(f);
    return (u & 0x80000000u) ? ~u : (u | 0x80000000u);
}
__device__ __forceinline__ float dec_f(unsigned u) {
    unsigned b = (u & 0x80000000u) ? (u ^ 0x80000000u) : ~u;
    return __uint_as_float(b);
}

__device__ __forceinline__ float wave_sum64(float v) {
    #pragma unroll
    for (int m = 1; m < 64; m <<= 1) v += __shfl_xor(v, m, 64);
    return v;
}

// ---- init correction_max buffer to encoded -inf (ws is poisoned 0xAA) ----
__global__ void init_cmax(unsigned* __restrict__ cmax) {
    int i = blockIdx.x * 256 + threadIdx.x;
    if (i < BATCH * HWSZ) cmax[i] = 0x007FFFFFu;  // enc(-inf)
}

// ---- per-position channel-vector normalization; one wave per position ----
// src/tgt layout [b][c][H*W]; outputs [b][pos][c] row-major
__global__ void normalize_kernel(const float* __restrict__ src,
                                 const float* __restrict__ tgt,
                                 float* __restrict__ s_hat,
                                 float* __restrict__ t_hat) {
    int wid = (blockIdx.x * blockDim.x + threadIdx.x) >> 6;  // position id
    int lane = threadIdx.x & 63;                              // channel
    int b = wid / HWSZ, m = wid - b * HWSZ;
    size_t gidx = (size_t)(b * CH + lane) * HWSZ + m;
    float s = src[gidx];
    float t = tgt[gidx];
    float ns = sqrtf(wave_sum64(s * s));
    float nt = sqrtf(wave_sum64(t * t));
    s_hat[(size_t)wid * CH + lane] = s / (ns + EPSV);
    t_hat[(size_t)wid * CH + lane] = t / (nt + EPSV);
}

// ---- GEMM-with-max: cmax[b][m] = max_n  sum_c s_hat[b][n][c]*t_hat[b][m][c] ----
// 128x128 tile, K=64 resident in LDS, 8x8 microtile/thread (split 4+4 at +64)
__global__ __launch_bounds__(256) void corrmax_kernel(const float* __restrict__ s_hat,
                                                      const float* __restrict__ t_hat,
                                                      unsigned* __restrict__ cmax) {
    __shared__ float As[CH][TM + 4];   // [c][n], row stride 132 floats (528B, 16B-mult)
    __shared__ float Bs[CH][TM + 4];   // [c][m]
    int b  = blockIdx.z;
    int m0 = blockIdx.x * TM;
    int n0 = blockIdx.y * TM;
    int t  = threadIdx.x;

    // stage: global [pos][c] -> LDS [c][pos_local]
    #pragma unroll
    for (int r = 0; r < (TM * CH) / 256; ++r) {   // 32 iters
        int e  = r * 256 + t;
        int nl = e >> 6;
        int c  = e & 63;
        As[c][nl] = s_hat[((size_t)b * HWSZ + n0 + nl) * CH + c];
        Bs[c][nl] = t_hat[((size_t)b * HWSZ + m0 + nl) * CH + c];
    }
    __syncthreads();

    int tx = t & 15, ty = t >> 4;
    float acc[8][8];
    #pragma unroll
    for (int i = 0; i < 8; ++i)
        #pragma unroll
        for (int j = 0; j < 8; ++j) acc[i][j] = 0.f;

    #pragma unroll 4
    for (int c = 0; c < CH; ++c) {
        float4 a0 = *(const float4*)&As[c][ty * 4];
        float4 a1 = *(const float4*)&As[c][64 + ty * 4];
        float4 b0 = *(const float4*)&Bs[c][tx * 4];
        float4 b1 = *(const float4*)&Bs[c][64 + tx * 4];
        float av[8] = {a0.x, a0.y, a0.z, a0.w, a1.x, a1.y, a1.z, a1.w};
        float bv[8] = {b0.x, b0.y, b0.z, b0.w, b1.x, b1.y, b1.z, b1.w};
        #pragma unroll
        for (int i = 0; i < 8; ++i)
            #pragma unroll
            for (int j = 0; j < 8; ++j)
                acc[i][j] = fmaf(av[i], bv[j], acc[i][j]);
    }

    // thread-local column max over this thread's 8 rows
    float lmax[8];
    #pragma unroll
    for (int j = 0; j < 8; ++j) {
        float mx = acc[0][j];
        #pragma unroll
        for (int i = 1; i < 8; ++i) mx = fmaxf(mx, acc[i][j]);
        lmax[j] = mx;
    }

    // reduce across ty (16 partials per column) via LDS (reuse As)
    __syncthreads();
    float* red = &As[0][0];   // need 16*128 = 2048 floats
    #pragma unroll
    for (int j = 0; j < 8; ++j) {
        int col = (j < 4) ? (tx * 4 + j) : (64 + tx * 4 + (j - 4));
        red[ty * TM + col] = lmax[j];
    }
    __syncthreads();
    if (t < TM) {
        float mx = red[t];
        #pragma unroll
        for (int r = 1; r < 16; ++r) mx = fmaxf(mx, red[r * TM + t]);
        atomicMax(&cmax[b * HWSZ + m0 + t], enc_f(mx));
    }
}

// ---- bilinear warp + cosine similarity + loss map; one wave per position ----
__global__ void sample_kernel(const float* __restrict__ tgt,
                              const float* __restrict__ src,
                              const float* __restrict__ flow,
                              const float* __restrict__ att,
                              const unsigned* __restrict__ cmax,
                              float* __restrict__ contrib) {
    int wid  = (blockIdx.x * blockDim.x + threadIdx.x) >> 6;  // position
    int lane = threadIdx.x & 63;                               // channel
    int b = wid / HWSZ, m = wid - b * HWSZ;
    int y = m / WID, x = m - y * WID;
    int fy = y >> 2, fx = x >> 2;  // nearest: (i*24)//96 == i//4

    float flow_x = flow[((b * 2 + 0) * 24 + fy) * 24 + fx];
    float flow_y = flow[((b * 2 + 1) * 24 + fy) * 24 + fx];

    // mirror the reference arithmetic exactly
    float gx = 2.f * ((float)x / (WID - 1)) - 1.f + 2.f * flow_x / (float)WID;
    float gy = 2.f * ((float)y / (HEI - 1)) - 1.f + 2.f * flow_y / (float)HEI;
    float sx = (gx + 1.f) * 0.5f * (WID - 1);
    float sy = (gy + 1.f) * 0.5f * (HEI - 1);
    float x0f = floorf(sx), y0f = floorf(sy);
    float wx1 = sx - x0f, wy1 = sy - y0f;
    float wx0 = 1.f - wx1, wy0 = 1.f - wy1;
    int x0 = (int)x0f, y0 = (int)y0f;

    const float* sp = src + (size_t)(b * CH + lane) * HWSZ;

    auto gather = [&](int ix, int iy) -> float {
        bool valid = (ix >= 0) && (ix < WID) && (iy >= 0) && (iy < HEI);
        int cx = min(max(ix, 0), WID - 1);
        int cy = min(max(iy, 0), HEI - 1);
        float v = sp[cy * WID + cx];
        return valid ? v : 0.f;
    };

    float v = gather(x0, y0)         * wx0 * wy0
            + gather(x0 + 1, y0)     * wx1 * wy0
            + gather(x0, y0 + 1)     * wx0 * wy1
            + gather(x0 + 1, y0 + 1) * wx1 * wy1;

    float tv = tgt[(size_t)(b * CH + lane) * HWSZ + m];

    float dot = wave_sum64(v * tv);
    float n1s = wave_sum64(v * v);
    float n2s = wave_sum64(tv * tv);

    if (lane == 0) {
        float n1 = sqrtf(n1s), n2 = sqrtf(n2s);
        float cs = dot / (fmaxf(n1, EPSV) * fmaxf(n2, EPSV));
        float cm = dec_f(cmax[wid]);
        float lm = expf(-cs / (cm + EPSV));
        float a  = att[(b * 24 + fy) * 24 + fx];
        contrib[wid] = a * (lm - expf(-1.0f));
    }
}

// ---- final mean over B*HW contributions ----
__global__ void reduce_kernel(const float* __restrict__ contrib, float* __restrict__ out) {
    __shared__ float sdata[4];
    int t = threadIdx.x;
    float s = 0.f;
    for (int i = t; i < BATCH * HWSZ; i += 256) s += contrib[i];
    s = wave_sum64(s);
    if ((t & 63) == 0) sdata[t >> 6] = s;
    __syncthreads();
    if (t == 0) out[0] = (sdata[0] + sdata[1] + sdata[2] + sdata[3]) / (float)(BATCH * HWSZ);
}

extern "C" void kernel_launch(void* const* d_in, const int* in_sizes, int n_in,
                              void* d_out, int out_size, void* d_ws, size_t ws_size,
                              hipStream_t stream) {
    const float* target_vgg = (const float*)d_in[0];
    const float* source_vgg = (const float*)d_in[1];
    const float* flow       = (const float*)d_in[2];
    const float* attention  = (const float*)d_in[3];
    float* out = (float*)d_out;

    float*    s_hat   = (float*)d_ws;                            // B*HW*C
    float*    t_hat   = s_hat + (size_t)BATCH * HWSZ * CH;       // B*HW*C
    unsigned* cmax    = (unsigned*)(t_hat + (size_t)BATCH * HWSZ * CH);  // B*HW
    float*    contrib = (float*)(cmax + BATCH * HWSZ);           // B*HW

    init_cmax<<<(BATCH * HWSZ + 255) / 256, 256, 0, stream>>>(cmax);
    normalize_kernel<<<(BATCH * HWSZ) / 4, 256, 0, stream>>>(source_vgg, target_vgg, s_hat, t_hat);
    dim3 g2(HWSZ / TM, HWSZ / TM, BATCH);
    corrmax_kernel<<<g2, 256, 0, stream>>>(s_hat, t_hat, cmax);
    sample_kernel<<<(BATCH * HWSZ) / 4, 256, 0, stream>>>(target_vgg, source_vgg, flow, attention, cmax, contrib);
    reduce_kernel<<<1, 256, 0, stream>>>(contrib, out);
}

// Round 2
// 131.773 us; speedup vs baseline: 2.8357x; 2.8357x over previous
//
#include <hip/hip_runtime.h>
#include <math.h>

#define BATCH 2
#define CH 64
#define WID 96
#define HEI 96
#define HWSZ 9216          // 96*96
#define EPSV 1e-8f
#define NSPLIT 8           // n-dimension split across blocks in corrmax

typedef __attribute__((ext_vector_type(8))) short short8v;  // 8 bf16 (4 VGPRs)
typedef __attribute__((ext_vector_type(4))) float f32x4;

// ---- order-preserving float<->uint encoding for atomicMax on floats ----
__device__ __forceinline__ unsigned enc_f(float f) {
    unsigned u = __float_as_uint(f);
    return (u & 0x80000000u) ? ~u : (u | 0x80000000u);
}
__device__ __forceinline__ float dec_f(unsigned u) {
    unsigned b = (u & 0x80000000u) ? (u ^ 0x80000000u) : ~u;
    return __uint_as_float(b);
}

__device__ __forceinline__ unsigned short f2bf(float f) {  // RNE bf16
    unsigned u = __float_as_uint(f);
    unsigned r = ((u >> 16) & 1u) + 0x7fffu;
    return (unsigned short)((u + r) >> 16);
}

__device__ __forceinline__ float wave_sum64(float v) {
    #pragma unroll
    for (int m = 1; m < 64; m <<= 1) v += __shfl_xor(v, m, 64);
    return v;
}

// ---- init: cmax to encoded -inf, loss accumulator to 0 ----
__global__ void init_kernel(unsigned* __restrict__ cmax, float* __restrict__ acc) {
    int i = blockIdx.x * 256 + threadIdx.x;
    if (i < BATCH * HWSZ) cmax[i] = 0x007FFFFFu;  // enc(-inf)
    if (i == 0) acc[0] = 0.f;
}

// ---- normalize: [b][c][HW] fp32 -> [b][pos][c] bf16 unit vectors ----
// Block handles 64 positions; LDS transpose so both global reads and writes
// are lane-contiguous.
__global__ __launch_bounds__(256) void normalize_kernel(const float* __restrict__ src,
                                                        const float* __restrict__ tgt,
                                                        unsigned short* __restrict__ s_hat,
                                                        unsigned short* __restrict__ t_hat) {
    __shared__ float ss[64][65];
    __shared__ float tt[64][65];
    __shared__ float red[2][4][64];
    __shared__ float rinv[2][64];
    int blk = blockIdx.x;                 // 0..287
    int b = blk / (HWSZ / 64);
    int p0 = (blk % (HWSZ / 64)) * 64;
    int t = threadIdx.x;
    int q = t >> 6, pl = t & 63;

    #pragma unroll
    for (int r = 0; r < 16; ++r) {
        int c = r * 4 + q;
        ss[c][pl] = src[(size_t)(b * CH + c) * HWSZ + p0 + pl];
        tt[c][pl] = tgt[(size_t)(b * CH + c) * HWSZ + p0 + pl];
    }
    __syncthreads();

    float as = 0.f, at = 0.f;
    #pragma unroll
    for (int i = 0; i < 16; ++i) {
        int c = q * 16 + i;
        float x = ss[c][pl]; as += x * x;
        float y = tt[c][pl]; at += y * y;
    }
    red[0][q][pl] = as; red[1][q][pl] = at;
    __syncthreads();
    if (t < 128) {
        int which = t >> 6, p = t & 63;
        float n = red[which][0][p] + red[which][1][p] + red[which][2][p] + red[which][3][p];
        rinv[which][p] = 1.f / (sqrtf(n) + EPSV);
    }
    __syncthreads();

    #pragma unroll
    for (int r = 0; r < 16; ++r) {
        int e = r * 256 + t;
        int p = e >> 6, c = e & 63;
        s_hat[((size_t)b * HWSZ + p0 + p) * CH + c] = f2bf(ss[c][p] * rinv[0][p]);
        t_hat[((size_t)b * HWSZ + p0 + p) * CH + c] = f2bf(tt[c][p] * rinv[1][p]);
    }
}

// ---- MFMA GEMM-with-max: cmax[b][m] = max_n  s_hat[b][n][:]·t_hat[b][m][:] ----
// No LDS: fragments load straight from global ([pos][c] layout makes the
// fragment read a coalesced 2KB/wave chunk). Each wave owns 64 m (4 groups of
// 16, B-frags hoisted into registers) and streams an n-chunk of HWSZ/NSPLIT.
__global__ __launch_bounds__(256) void corrmax_kernel(const unsigned short* __restrict__ s_hat,
                                                      const unsigned short* __restrict__ t_hat,
                                                      unsigned* __restrict__ cmax) {
    int b = blockIdx.z;
    int wave = threadIdx.x >> 6;
    int lane = threadIdx.x & 63;
    int lrow = lane & 15;                 // pos-in-group (A row / B col)
    int g16  = lane >> 4;                 // k-group (8 bf16 each)
    int m_base = blockIdx.x * 256 + wave * 64;
    const size_t bofs = (size_t)b * HWSZ * CH;

    short8v bf[4][2];
    #pragma unroll
    for (int gm = 0; gm < 4; ++gm) {
        const unsigned short* p = t_hat + bofs + (size_t)(m_base + gm * 16 + lrow) * CH + g16 * 8;
        bf[gm][0] = *(const short8v*)p;
        bf[gm][1] = *(const short8v*)(p + 32);
    }

    f32x4 zero = {0.f, 0.f, 0.f, 0.f};
    f32x4 rmax[4];
    #pragma unroll
    for (int gm = 0; gm < 4; ++gm)
        rmax[gm] = (f32x4){-INFINITY, -INFINITY, -INFINITY, -INFINITY};

    int n0 = blockIdx.y * (HWSZ / NSPLIT);
    const unsigned short* ap = s_hat + bofs + ((size_t)n0 + lrow) * CH + g16 * 8;

    #pragma unroll 2
    for (int it = 0; it < HWSZ / NSPLIT / 16; ++it) {   // 72 n-groups
        short8v a0 = *(const short8v*)ap;
        short8v a1 = *(const short8v*)(ap + 32);
        ap += 16 * CH;
        #pragma unroll
        for (int gm = 0; gm < 4; ++gm) {
            f32x4 acc = __builtin_amdgcn_mfma_f32_16x16x32_bf16(a0, bf[gm][0], zero, 0, 0, 0);
            acc = __builtin_amdgcn_mfma_f32_16x16x32_bf16(a1, bf[gm][1], acc, 0, 0, 0);
            rmax[gm][0] = fmaxf(rmax[gm][0], acc[0]);
            rmax[gm][1] = fmaxf(rmax[gm][1], acc[1]);
            rmax[gm][2] = fmaxf(rmax[gm][2], acc[2]);
            rmax[gm][3] = fmaxf(rmax[gm][3], acc[3]);
        }
    }

    #pragma unroll
    for (int gm = 0; gm < 4; ++gm) {
        float v = fmaxf(fmaxf(rmax[gm][0], rmax[gm][1]), fmaxf(rmax[gm][2], rmax[gm][3]));
        v = fmaxf(v, __shfl_xor(v, 16, 64));
        v = fmaxf(v, __shfl_xor(v, 32, 64));
        if (g16 == 0)
            atomicMax(&cmax[b * HWSZ + m_base + gm * 16 + lrow], enc_f(v));
    }
}

// ---- bilinear warp + cosine sim + loss map + partial sum ----
// thread = position (lanes contiguous in x -> coalesced); channels split 4-way
// across the block's 4 waves, reduced via LDS.
__global__ __launch_bounds__(256) void sample_kernel(const float* __restrict__ tgt,
                                                     const float* __restrict__ src,
                                                     const float* __restrict__ flow,
                                                     const float* __restrict__ att,
                                                     const unsigned* __restrict__ cmax,
                                                     float* __restrict__ acc_out) {
    __shared__ float red[3][4][64];
    int blk = blockIdx.x;                 // 0..287
    int t = threadIdx.x;
    int q = t >> 6, pl = t & 63;
    int b = blk / (HWSZ / 64);
    int m = (blk % (HWSZ / 64)) * 64 + pl;
    int y = m / WID, x = m - y * WID;
    int fy = y >> 2, fx = x >> 2;

    float flow_x = flow[((b * 2 + 0) * 24 + fy) * 24 + fx];
    float flow_y = flow[((b * 2 + 1) * 24 + fy) * 24 + fx];

    float gx = 2.f * ((float)x / (WID - 1)) - 1.f + 2.f * flow_x / (float)WID;
    float gy = 2.f * ((float)y / (HEI - 1)) - 1.f + 2.f * flow_y / (float)HEI;
    float sx = (gx + 1.f) * 0.5f * (WID - 1);
    float sy = (gy + 1.f) * 0.5f * (HEI - 1);
    float x0f = floorf(sx), y0f = floorf(sy);
    float wx1 = sx - x0f, wy1 = sy - y0f;
    float wx0 = 1.f - wx1, wy0 = 1.f - wy1;
    int x0 = (int)x0f, y0 = (int)y0f;

    int cx0 = min(max(x0, 0), WID - 1), cx1 = min(max(x0 + 1, 0), WID - 1);
    int cy0 = min(max(y0, 0), HEI - 1), cy1 = min(max(y0 + 1, 0), HEI - 1);
    float ok00 = (x0 >= 0 && x0 < WID && y0 >= 0 && y0 < HEI) ? 1.f : 0.f;
    float ok10 = (x0 + 1 >= 0 && x0 + 1 < WID && y0 >= 0 && y0 < HEI) ? 1.f : 0.f;
    float ok01 = (x0 >= 0 && x0 < WID && y0 + 1 >= 0 && y0 + 1 < HEI) ? 1.f : 0.f;
    float ok11 = (x0 + 1 >= 0 && x0 + 1 < WID && y0 + 1 >= 0 && y0 + 1 < HEI) ? 1.f : 0.f;
    float w00 = wx0 * wy0 * ok00, w10 = wx1 * wy0 * ok10;
    float w01 = wx0 * wy1 * ok01, w11 = wx1 * wy1 * ok11;
    int i00 = cy0 * WID + cx0, i10 = cy0 * WID + cx1;
    int i01 = cy1 * WID + cx0, i11 = cy1 * WID + cx1;

    const float* sb = src + (size_t)b * CH * HWSZ;
    const float* tb = tgt + (size_t)b * CH * HWSZ;

    float dot = 0.f, n1 = 0.f, n2 = 0.f;
    #pragma unroll 4
    for (int i = 0; i < 16; ++i) {
        int c = q * 16 + i;
        const float* sc = sb + (size_t)c * HWSZ;
        float v = w00 * sc[i00] + w10 * sc[i10] + w01 * sc[i01] + w11 * sc[i11];
        float tv = tb[(size_t)c * HWSZ + m];
        dot += v * tv; n1 += v * v; n2 += tv * tv;
    }
    red[0][q][pl] = dot; red[1][q][pl] = n1; red[2][q][pl] = n2;
    __syncthreads();

    if (t < 64) {
        float d = red[0][0][pl] + red[0][1][pl] + red[0][2][pl] + red[0][3][pl];
        float a1 = red[1][0][pl] + red[1][1][pl] + red[1][2][pl] + red[1][3][pl];
        float a2 = red[2][0][pl] + red[2][1][pl] + red[2][2][pl] + red[2][3][pl];
        float cs = d / (fmaxf(sqrtf(a1), EPSV) * fmaxf(sqrtf(a2), EPSV));
        float cm = dec_f(cmax[b * HWSZ + m]);
        float lm = expf(-cs / (cm + EPSV));
        float a = att[(b * 24 + fy) * 24 + fx];
        float contrib = a * (lm - 0.36787944117144233f);
        contrib = wave_sum64(contrib);
        if (t == 0) atomicAdd(acc_out, contrib);
    }
}

__global__ void finalize_kernel(const float* __restrict__ acc, float* __restrict__ out) {
    out[0] = acc[0] / (float)(BATCH * HWSZ);
}

extern "C" void kernel_launch(void* const* d_in, const int* in_sizes, int n_in,
                              void* d_out, int out_size, void* d_ws, size_t ws_size,
                              hipStream_t stream) {
    const float* target_vgg = (const float*)d_in[0];
    const float* source_vgg = (const float*)d_in[1];
    const float* flow       = (const float*)d_in[2];
    const float* attention  = (const float*)d_in[3];
    float* out = (float*)d_out;

    unsigned short* s_hat = (unsigned short*)d_ws;                       // B*HW*C bf16
    unsigned short* t_hat = s_hat + (size_t)BATCH * HWSZ * CH;           // B*HW*C bf16
    unsigned* cmax = (unsigned*)(t_hat + (size_t)BATCH * HWSZ * CH);     // B*HW u32
    float* acc = (float*)(cmax + BATCH * HWSZ);                          // 1 f32

    init_kernel<<<(BATCH * HWSZ + 255) / 256, 256, 0, stream>>>(cmax, acc);
    normalize_kernel<<<BATCH * HWSZ / 64, 256, 0, stream>>>(source_vgg, target_vgg, s_hat, t_hat);
    dim3 g2(HWSZ / 256, NSPLIT, BATCH);
    corrmax_kernel<<<g2, 256, 0, stream>>>(s_hat, t_hat, cmax);
    sample_kernel<<<BATCH * HWSZ / 64, 256, 0, stream>>>(target_vgg, source_vgg, flow, attention, cmax, acc);
    finalize_kernel<<<1, 1, 0, stream>>>(acc, out);
}

// Round 4
// 127.373 us; speedup vs baseline: 2.9336x; 1.0345x over previous
//
#include <hip/hip_runtime.h>
#include <math.h>

#define BATCH 2
#define CH 64
#define WID 96
#define HEI 96
#define HWSZ 9216          // 96*96
#define EPSV 1e-8f
#define NSPLIT 32          // n-dimension split across blocks in corrmax

typedef __attribute__((ext_vector_type(8))) short short8v;  // 8 bf16 (4 VGPRs)
typedef __attribute__((ext_vector_type(4))) float f32x4;

__device__ __forceinline__ unsigned short f2bf(float f) {  // RNE bf16
    unsigned u = __float_as_uint(f);
    unsigned r = ((u >> 16) & 1u) + 0x7fffu;
    return (unsigned short)((u + r) >> 16);
}

__device__ __forceinline__ float wave_sum64(float v) {
    #pragma unroll
    for (int m = 1; m < 64; m <<= 1) v += __shfl_xor(v, m, 64);
    return v;
}

// ---- normalize: [b][c][HW] fp32 -> [b][pos][c] bf16 unit vectors ----
// 32 positions per block (576 blocks); float4 global reads, ushort4 writes.
__global__ __launch_bounds__(256) void normalize_kernel(const float* __restrict__ src,
                                                        const float* __restrict__ tgt,
                                                        unsigned short* __restrict__ s_hat,
                                                        unsigned short* __restrict__ t_hat) {
    __shared__ float ss[CH][33];
    __shared__ float tt[CH][33];
    __shared__ float red[2][8][32];
    __shared__ float rinv[2][32];
    int b  = blockIdx.x / (HWSZ / 32);
    int p0 = (blockIdx.x % (HWSZ / 32)) * 32;
    int t  = threadIdx.x;

    // read phase: round r covers c = r*32 + (t>>3), f4 = (t&7)*4
    #pragma unroll
    for (int r = 0; r < 2; ++r) {
        int c  = r * 32 + (t >> 3);
        int f4 = (t & 7) * 4;
        float4 v = *(const float4*)&src[(size_t)(b * CH + c) * HWSZ + p0 + f4];
        ss[c][f4] = v.x; ss[c][f4 + 1] = v.y; ss[c][f4 + 2] = v.z; ss[c][f4 + 3] = v.w;
        float4 u = *(const float4*)&tgt[(size_t)(b * CH + c) * HWSZ + p0 + f4];
        tt[c][f4] = u.x; tt[c][f4 + 1] = u.y; tt[c][f4 + 2] = u.z; tt[c][f4 + 3] = u.w;
    }
    __syncthreads();

    // sumsq: q = t>>5 (channel octet), pl = t&31 (position)
    {
        int q = t >> 5, pl = t & 31;
        float as = 0.f, at = 0.f;
        #pragma unroll
        for (int i = 0; i < 8; ++i) {
            float x = ss[q * 8 + i][pl]; as += x * x;
            float y = tt[q * 8 + i][pl]; at += y * y;
        }
        red[0][q][pl] = as; red[1][q][pl] = at;
    }
    __syncthreads();
    if (t < 64) {
        int which = t >> 5, p = t & 31;
        float n = 0.f;
        #pragma unroll
        for (int g = 0; g < 8; ++g) n += red[which][g][p];
        rinv[which][p] = 1.f / (sqrtf(n) + EPSV);
    }
    __syncthreads();

    // write phase: e = r*256+t -> pos = e>>4, c4 = (e&15)*4; ushort4 stores
    #pragma unroll
    for (int r = 0; r < 2; ++r) {
        int e = r * 256 + t;
        int p = e >> 4, c4 = (e & 15) * 4;
        float ri_s = rinv[0][p], ri_t = rinv[1][p];
        ushort4 os, ot;
        os.x = f2bf(ss[c4][p] * ri_s);     os.y = f2bf(ss[c4 + 1][p] * ri_s);
        os.z = f2bf(ss[c4 + 2][p] * ri_s); os.w = f2bf(ss[c4 + 3][p] * ri_s);
        ot.x = f2bf(tt[c4][p] * ri_t);     ot.y = f2bf(tt[c4 + 1][p] * ri_t);
        ot.z = f2bf(tt[c4 + 2][p] * ri_t); ot.w = f2bf(tt[c4 + 3][p] * ri_t);
        *(ushort4*)&s_hat[((size_t)b * HWSZ + p0 + p) * CH + c4] = os;
        *(ushort4*)&t_hat[((size_t)b * HWSZ + p0 + p) * CH + c4] = ot;
    }
}

// ---- MFMA GEMM-with-max, partial over n-chunks: pmax[b][ny][m] ----
// No LDS, no atomics. Double-buffered A loads; fmax trees for v_max3 fusion.
__global__ __launch_bounds__(256) void corrmax_kernel(const unsigned short* __restrict__ s_hat,
                                                      const unsigned short* __restrict__ t_hat,
                                                      float* __restrict__ pmax) {
    int b = blockIdx.z;
    int wave = threadIdx.x >> 6;
    int lane = threadIdx.x & 63;
    int lrow = lane & 15;                 // pos-in-group
    int g16  = lane >> 4;                 // k-group (8 bf16 each)
    int m_base = blockIdx.x * 256 + wave * 64;
    const size_t bofs = (size_t)b * HWSZ * CH;

    short8v bf[4][2];
    #pragma unroll
    for (int gm = 0; gm < 4; ++gm) {
        const unsigned short* p = t_hat + bofs + (size_t)(m_base + gm * 16 + lrow) * CH + g16 * 8;
        bf[gm][0] = *(const short8v*)p;
        bf[gm][1] = *(const short8v*)(p + 32);
    }

    f32x4 zero = {0.f, 0.f, 0.f, 0.f};
    float rmax[4] = {-INFINITY, -INFINITY, -INFINITY, -INFINITY};

    int n0 = blockIdx.y * (HWSZ / NSPLIT);
    const unsigned short* ap = s_hat + bofs + ((size_t)n0 + lrow) * CH + g16 * 8;

    const int NIT = HWSZ / NSPLIT / 16;   // 18 n-groups per chunk
    short8v a0 = *(const short8v*)ap;
    short8v a1 = *(const short8v*)(ap + 32);
    ap += 16 * CH;

    for (int it = 0; it < NIT - 1; ++it) {
        short8v na0 = *(const short8v*)ap;
        short8v na1 = *(const short8v*)(ap + 32);
        ap += 16 * CH;
        #pragma unroll
        for (int gm = 0; gm < 4; ++gm) {
            f32x4 acc = __builtin_amdgcn_mfma_f32_16x16x32_bf16(a0, bf[gm][0], zero, 0, 0, 0);
            acc = __builtin_amdgcn_mfma_f32_16x16x32_bf16(a1, bf[gm][1], acc, 0, 0, 0);
            float tmx = fmaxf(fmaxf(acc[0], acc[1]), acc[2]);       // -> v_max3
            rmax[gm] = fmaxf(fmaxf(tmx, acc[3]), rmax[gm]);         // -> v_max3
        }
        a0 = na0; a1 = na1;
    }
    #pragma unroll
    for (int gm = 0; gm < 4; ++gm) {
        f32x4 acc = __builtin_amdgcn_mfma_f32_16x16x32_bf16(a0, bf[gm][0], zero, 0, 0, 0);
        acc = __builtin_amdgcn_mfma_f32_16x16x32_bf16(a1, bf[gm][1], acc, 0, 0, 0);
        float tmx = fmaxf(fmaxf(acc[0], acc[1]), acc[2]);
        rmax[gm] = fmaxf(fmaxf(tmx, acc[3]), rmax[gm]);
    }

    #pragma unroll
    for (int gm = 0; gm < 4; ++gm) {
        float v = rmax[gm];
        v = fmaxf(v, __shfl_xor(v, 16, 64));
        v = fmaxf(v, __shfl_xor(v, 32, 64));
        if (g16 == 0)
            pmax[((size_t)b * NSPLIT + blockIdx.y) * HWSZ + m_base + gm * 16 + lrow] = v;
    }
}

// ---- bilinear warp + cosine sim + partial-max reduce + loss partial sum ----
// 32 positions per block (576 blocks); q = t>>5 channel octet, pl = t&31 pos.
__global__ __launch_bounds__(256) void sample_kernel(const float* __restrict__ tgt,
                                                     const float* __restrict__ src,
                                                     const float* __restrict__ flow,
                                                     const float* __restrict__ att,
                                                     const float* __restrict__ pmax,
                                                     float* __restrict__ bsum) {
    __shared__ float red[3][8][32];
    int blk = blockIdx.x;                 // 0..575
    int t = threadIdx.x;
    int q = t >> 5, pl = t & 31;
    int b = blk / (HWSZ / 32);
    int m = (blk % (HWSZ / 32)) * 32 + pl;
    int y = m / WID, x = m - y * WID;
    int fy = y >> 2, fx = x >> 2;

    float flow_x = flow[((b * 2 + 0) * 24 + fy) * 24 + fx];
    float flow_y = flow[((b * 2 + 1) * 24 + fy) * 24 + fx];

    float gx = 2.f * ((float)x / (WID - 1)) - 1.f + 2.f * flow_x / (float)WID;
    float gy = 2.f * ((float)y / (HEI - 1)) - 1.f + 2.f * flow_y / (float)HEI;
    float sx = (gx + 1.f) * 0.5f * (WID - 1);
    float sy = (gy + 1.f) * 0.5f * (HEI - 1);
    float x0f = floorf(sx), y0f = floorf(sy);
    float wx1 = sx - x0f, wy1 = sy - y0f;
    float wx0 = 1.f - wx1, wy0 = 1.f - wy1;
    int x0 = (int)x0f, y0 = (int)y0f;

    int cx0 = min(max(x0, 0), WID - 1), cx1 = min(max(x0 + 1, 0), WID - 1);
    int cy0 = min(max(y0, 0), HEI - 1), cy1 = min(max(y0 + 1, 0), HEI - 1);
    float ok00 = (x0 >= 0 && x0 < WID && y0 >= 0 && y0 < HEI) ? 1.f : 0.f;
    float ok10 = (x0 + 1 >= 0 && x0 + 1 < WID && y0 >= 0 && y0 < HEI) ? 1.f : 0.f;
    float ok01 = (x0 >= 0 && x0 < WID && y0 + 1 >= 0 && y0 + 1 < HEI) ? 1.f : 0.f;
    float ok11 = (x0 + 1 >= 0 && x0 + 1 < WID && y0 + 1 >= 0 && y0 + 1 < HEI) ? 1.f : 0.f;
    float w00 = wx0 * wy0 * ok00, w10 = wx1 * wy0 * ok10;
    float w01 = wx0 * wy1 * ok01, w11 = wx1 * wy1 * ok11;
    int i00 = cy0 * WID + cx0, i10 = cy0 * WID + cx1;
    int i01 = cy1 * WID + cx0, i11 = cy1 * WID + cx1;

    const float* sb = src + (size_t)b * CH * HWSZ;
    const float* tb = tgt + (size_t)b * CH * HWSZ;

    float dot = 0.f, n1 = 0.f, n2 = 0.f;
    #pragma unroll
    for (int i = 0; i < 8; ++i) {
        int c = q * 8 + i;
        const float* sc = sb + (size_t)c * HWSZ;
        float v = w00 * sc[i00] + w10 * sc[i10] + w01 * sc[i01] + w11 * sc[i11];
        float tv = tb[(size_t)c * HWSZ + m];
        dot += v * tv; n1 += v * v; n2 += tv * tv;
    }
    red[0][q][pl] = dot; red[1][q][pl] = n1; red[2][q][pl] = n2;
    __syncthreads();

    float contrib = 0.f;
    if (t < 32) {
        float d = 0.f, a1 = 0.f, a2 = 0.f;
        #pragma unroll
        for (int g = 0; g < 8; ++g) {
            d += red[0][g][pl]; a1 += red[1][g][pl]; a2 += red[2][g][pl];
        }
        float cm = -INFINITY;
        #pragma unroll 8
        for (int ny = 0; ny < NSPLIT; ++ny)
            cm = fmaxf(cm, pmax[((size_t)b * NSPLIT + ny) * HWSZ + m]);
        float cs = d / (fmaxf(sqrtf(a1), EPSV) * fmaxf(sqrtf(a2), EPSV));
        float lm = expf(-cs / (cm + EPSV));
        float a = att[(b * 24 + fy) * 24 + fx];
        contrib = a * (lm - 0.36787944117144233f);
    }
    if (t < 64) {
        contrib = wave_sum64(contrib);
        if (t == 0) bsum[blk] = contrib;
    }
}

// ---- final mean over block partial sums ----
__global__ void finalize_kernel(const float* __restrict__ bsum, float* __restrict__ out) {
    __shared__ float sdata[4];
    int t = threadIdx.x;
    float s = 0.f;
    for (int i = t; i < BATCH * HWSZ / 32; i += 256) s += bsum[i];
    s = wave_sum64(s);
    if ((t & 63) == 0) sdata[t >> 6] = s;
    __syncthreads();
    if (t == 0) out[0] = (sdata[0] + sdata[1] + sdata[2] + sdata[3]) / (float)(BATCH * HWSZ);
}

extern "C" void kernel_launch(void* const* d_in, const int* in_sizes, int n_in,
                              void* d_out, int out_size, void* d_ws, size_t ws_size,
                              hipStream_t stream) {
    const float* target_vgg = (const float*)d_in[0];
    const float* source_vgg = (const float*)d_in[1];
    const float* flow       = (const float*)d_in[2];
    const float* attention  = (const float*)d_in[3];
    float* out = (float*)d_out;

    unsigned short* s_hat = (unsigned short*)d_ws;                       // B*HW*C bf16
    unsigned short* t_hat = s_hat + (size_t)BATCH * HWSZ * CH;           // B*HW*C bf16
    float* pmax = (float*)(t_hat + (size_t)BATCH * HWSZ * CH);           // B*NSPLIT*HW f32
    float* bsum = pmax + (size_t)BATCH * NSPLIT * HWSZ;                  // B*HW/32 f32

    normalize_kernel<<<BATCH * HWSZ / 32, 256, 0, stream>>>(source_vgg, target_vgg, s_hat, t_hat);
    dim3 g2(HWSZ / 256, NSPLIT, BATCH);
    corrmax_kernel<<<g2, 256, 0, stream>>>(s_hat, t_hat, pmax);
    sample_kernel<<<BATCH * HWSZ / 32, 256, 0, stream>>>(target_vgg, source_vgg, flow, attention, pmax, bsum);
    finalize_kernel<<<1, 256, 0, stream>>>(bsum, out);
}